// Round 1
// baseline (2100.070 us; speedup 1.0000x reference)
//
#include <hip/hip_runtime.h>
#include <hip/hip_bf16.h>

#define CDIM 256
#define MDIM 196
#define MATN (CDIM*CDIM)          // 65536
#define DTRI (CDIM*(CDIM+1)/2)    // 32896

// ---------- per-row means over M ----------
__global__ void means_kernel(const float* __restrict__ x, float* __restrict__ means, int nrows) {
    int row  = blockIdx.x * 4 + (threadIdx.x >> 6);
    int lane = threadIdx.x & 63;
    if (row >= nrows) return;
    const float* xr = x + (size_t)row * MDIM;
    float s = 0.f;
    for (int m = lane; m < MDIM; m += 64) s += xr[m];
#pragma unroll
    for (int off = 32; off > 0; off >>= 1) s += __shfl_down(s, off);
    if (lane == 0) means[row] = s * (1.f / MDIM);
}

// ---------- covariance: A[b] = (1/M) x x^T - mu mu^T ----------
__global__ __launch_bounds__(256) void covpool_kernel(const float* __restrict__ x,
        const float* __restrict__ means, float* __restrict__ A) {
    int b  = blockIdx.y;
    int r0 = (blockIdx.x >> 2) * 64;
    int c0 = (blockIdx.x & 3) * 64;
    const float* xb = x + (size_t)b * CDIM * MDIM;
    __shared__ float As[16][68];
    __shared__ float Bs[16][68];
    int tid = threadIdx.x;
    int ty = tid >> 4, tx = tid & 15;
    float acc[4][4] = {};
    int kl = tid & 15, m0 = tid >> 4;
    for (int k0 = 0; k0 < MDIM; k0 += 16) {
        int k = k0 + kl;
        bool kok = (k < MDIM);
#pragma unroll
        for (int i = 0; i < 4; i++) {
            int ml = m0 + 16 * i;
            As[kl][ml] = kok ? xb[(size_t)(r0 + ml) * MDIM + k] : 0.f;
            Bs[kl][ml] = kok ? xb[(size_t)(c0 + ml) * MDIM + k] : 0.f;
        }
        __syncthreads();
#pragma unroll
        for (int kk = 0; kk < 16; kk++) {
            float4 av = *(const float4*)&As[kk][ty * 4];
            float4 bv = *(const float4*)&Bs[kk][tx * 4];
            float aa[4] = {av.x, av.y, av.z, av.w};
            float bb[4] = {bv.x, bv.y, bv.z, bv.w};
#pragma unroll
            for (int i = 0; i < 4; i++)
#pragma unroll
                for (int j = 0; j < 4; j++)
                    acc[i][j] = fmaf(aa[i], bb[j], acc[i][j]);
        }
        __syncthreads();
    }
    const float* mub = means + (size_t)b * CDIM;
    float mi[4], mj[4];
#pragma unroll
    for (int i = 0; i < 4; i++) { mi[i] = mub[r0 + ty * 4 + i]; mj[i] = mub[c0 + tx * 4 + i]; }
    float* Ab = A + (size_t)b * MATN;
#pragma unroll
    for (int i = 0; i < 4; i++)
#pragma unroll
        for (int j = 0; j < 4; j++)
            Ab[(size_t)(r0 + ty * 4 + i) * CDIM + c0 + tx * 4 + j] =
                acc[i][j] * (1.f / MDIM) - mi[i] * mj[j];
}

// ---------- trace per batch ----------
__global__ void trace_kernel(const float* __restrict__ A, float* __restrict__ norm) {
    int b = blockIdx.x;
    int tid = threadIdx.x;
    float v = A[(size_t)b * MATN + (size_t)tid * (CDIM + 1)];
#pragma unroll
    for (int off = 32; off > 0; off >>= 1) v += __shfl_down(v, off);
    __shared__ float red[4];
    if ((tid & 63) == 0) red[tid >> 6] = v;
    __syncthreads();
    if (tid == 0) norm[b] = red[0] + red[1] + red[2] + red[3];
}

// ---------- Ahat = A/norm (in place), Z0 = 1.5 I - 0.5 Ahat ----------
__global__ void prep_kernel(float* __restrict__ A, float* __restrict__ Z,
                            const float* __restrict__ norm, int total4) {
    int stride = gridDim.x * blockDim.x;
    for (int idx = blockIdx.x * blockDim.x + threadIdx.x; idx < total4; idx += stride) {
        int e0 = idx << 2;
        int b = e0 >> 16;
        float inv = 1.f / norm[b];
        float4 a = ((const float4*)A)[idx];
        a.x *= inv; a.y *= inv; a.z *= inv; a.w *= inv;
        int rc = e0 & (MATN - 1);
        int r = rc >> 8, c = rc & 255;
        float4 z;
        z.x = (r == c     ? 1.5f : 0.f) - 0.5f * a.x;
        z.y = (r == c + 1 ? 1.5f : 0.f) - 0.5f * a.y;
        z.z = (r == c + 2 ? 1.5f : 0.f) - 0.5f * a.z;
        z.w = (r == c + 3 ? 1.5f : 0.f) - 0.5f * a.w;
        ((float4*)A)[idx] = a;
        ((float4*)Z)[idx] = z;
    }
}

// ---------- batched GEMM: D[b] = (alpha*A[b]@B[b] + beta*C[b]) * (norm? sqrt(norm[b]) : 1) ----------
__global__ __launch_bounds__(256) void bgemm_kernel(
        const float* __restrict__ A, const float* __restrict__ B,
        const float* __restrict__ Cm, float* __restrict__ D,
        float alpha, float beta, const float* __restrict__ norm) {
    int b  = blockIdx.y;
    int r0 = (blockIdx.x >> 2) * 64;
    int c0 = (blockIdx.x & 3) * 64;
    const float* Ab = A + (size_t)b * MATN;
    const float* Bb = B + (size_t)b * MATN;
    __shared__ float As[16][68];
    __shared__ float Bs[16][68];
    int tid = threadIdx.x;
    int ty = tid >> 4, tx = tid & 15;
    float acc[4][4] = {};
    int kl = tid & 15, m0 = tid >> 4;   // A-tile loader
    int n0 = tid & 63, k1 = tid >> 6;   // B-tile loader
    for (int k0 = 0; k0 < CDIM; k0 += 16) {
#pragma unroll
        for (int i = 0; i < 4; i++)
            As[kl][m0 + 16 * i] = Ab[(size_t)(r0 + m0 + 16 * i) * CDIM + k0 + kl];
#pragma unroll
        for (int i = 0; i < 4; i++)
            Bs[k1 + 4 * i][n0] = Bb[(size_t)(k0 + k1 + 4 * i) * CDIM + c0 + n0];
        __syncthreads();
#pragma unroll
        for (int kk = 0; kk < 16; kk++) {
            float4 av = *(const float4*)&As[kk][ty * 4];
            float4 bv = *(const float4*)&Bs[kk][tx * 4];
            float aa[4] = {av.x, av.y, av.z, av.w};
            float bb[4] = {bv.x, bv.y, bv.z, bv.w};
#pragma unroll
            for (int i = 0; i < 4; i++)
#pragma unroll
                for (int j = 0; j < 4; j++)
                    acc[i][j] = fmaf(aa[i], bb[j], acc[i][j]);
        }
        __syncthreads();
    }
    float sc = norm ? sqrtf(norm[b]) : 1.f;
    float* Db = D + (size_t)b * MATN;
#pragma unroll
    for (int i = 0; i < 4; i++) {
        int r = r0 + ty * 4 + i;
#pragma unroll
        for (int j = 0; j < 4; j++) {
            int c = c0 + tx * 4 + j;
            float v = alpha * acc[i][j];
            if (Cm) v += beta * Cm[(size_t)b * MATN + (size_t)r * CDIM + c];
            Db[(size_t)r * CDIM + c] = v * sc;
        }
    }
}

// ---------- triuvec + FC: out[b][k] = sum_triu Yf[b][i][j]*w[k][t(i,j)] + bias[k] ----------
__global__ void fc_kernel(const float* __restrict__ Yf, const float* __restrict__ w,
                          const float* __restrict__ bias, float* __restrict__ out, int b0) {
    int b = blockIdx.x;
    const float* Y = Yf + (size_t)b * MATN;
    int tid = threadIdx.x;
    const float* w0 = w;
    const float* w1 = w + DTRI;
    float a0 = 0.f, a1 = 0.f;
    for (int i = 0; i < CDIM; i++) {
        int j = tid;
        if (j >= i) {
            int t = i * CDIM - (i * (i - 1)) / 2 + (j - i);
            float v = Y[i * CDIM + j];
            a0 = fmaf(v, w0[t], a0);
            a1 = fmaf(v, w1[t], a1);
        }
    }
#pragma unroll
    for (int off = 32; off > 0; off >>= 1) { a0 += __shfl_down(a0, off); a1 += __shfl_down(a1, off); }
    __shared__ float s0[4], s1[4];
    int lane = tid & 63, wv = tid >> 6;
    if (lane == 0) { s0[wv] = a0; s1[wv] = a1; }
    __syncthreads();
    if (tid == 0) {
        out[(size_t)(b0 + b) * 2 + 0] = s0[0] + s0[1] + s0[2] + s0[3] + bias[0];
        out[(size_t)(b0 + b) * 2 + 1] = s1[0] + s1[1] + s1[2] + s1[3] + bias[1];
    }
}

extern "C" void kernel_launch(void* const* d_in, const int* in_sizes, int n_in,
                              void* d_out, int out_size, void* d_ws, size_t ws_size,
                              hipStream_t stream) {
    const float* x    = (const float*)d_in[0];
    const float* fc_w = (const float*)d_in[1];
    const float* fc_b = (const float*)d_in[2];
    float* out = (float*)d_out;
    int B = in_sizes[0] / (CDIM * MDIM);

    // workspace: 4 matrix buffers + means + norm per chunk batch
    size_t per_b = (size_t)4 * MATN * sizeof(float) + (size_t)CDIM * sizeof(float) + sizeof(float);
    int Bc = B;
    while (Bc > 1 && (size_t)Bc * per_b > ws_size) Bc >>= 1;

    char* p = (char*)d_ws;
    float* buf[4];
    for (int i = 0; i < 4; i++) { buf[i] = (float*)p; p += (size_t)Bc * MATN * sizeof(float); }
    float* means = (float*)p; p += (size_t)Bc * CDIM * sizeof(float);
    float* norm  = (float*)p;

    for (int b0 = 0; b0 < B; b0 += Bc) {
        int bc = (Bc < B - b0) ? Bc : (B - b0);
        const float* xb = x + (size_t)b0 * CDIM * MDIM;

        int nrows = bc * CDIM;
        means_kernel<<<(nrows + 3) / 4, 256, 0, stream>>>(xb, means, nrows);
        covpool_kernel<<<dim3(16, bc), 256, 0, stream>>>(xb, means, buf[0]);
        trace_kernel<<<bc, 256, 0, stream>>>(buf[0], norm);
        int total4 = bc * (MATN / 4);
        int pblocks = (total4 + 255) / 256; if (pblocks > 2048) pblocks = 2048;
        prep_kernel<<<pblocks, 256, 0, stream>>>(buf[0], buf[1], norm, total4);

        float* Ahat = buf[0];
        float* z = buf[1]; float* t1 = buf[2]; float* t2 = buf[3];
        dim3 ggrid(16, bc);
        // 3 inner NS iterations on Z only (Y_k == Ahat @ Z_k by commutativity)
        for (int it = 0; it < 3; it++) {
            bgemm_kernel<<<ggrid, 256, 0, stream>>>(Ahat, z, nullptr, t1, 1.f, 0.f, nullptr);   // Y = Ahat@Z
            bgemm_kernel<<<ggrid, 256, 0, stream>>>(z, t1, nullptr, t2, 1.f, 0.f, nullptr);     // P = Z@Y
            bgemm_kernel<<<ggrid, 256, 0, stream>>>(t2, z, z, t1, -0.5f, 1.5f, nullptr);        // Z' = -0.5 P@Z + 1.5 Z
            float* tmp = z; z = t1; t1 = tmp;
        }
        // final: Y3 = Ahat@Z3; P = Z3@Y3; Yfinal = sqrt(norm)*(1.5*Y3 - 0.5*Y3@P)
        bgemm_kernel<<<ggrid, 256, 0, stream>>>(Ahat, z, nullptr, t1, 1.f, 0.f, nullptr);
        bgemm_kernel<<<ggrid, 256, 0, stream>>>(z, t1, nullptr, t2, 1.f, 0.f, nullptr);
        bgemm_kernel<<<ggrid, 256, 0, stream>>>(t1, t2, t1, Ahat, -0.5f, 1.5f, norm);
        fc_kernel<<<bc, 256, 0, stream>>>(Ahat, fc_w, fc_b, out, b0);
    }
}

// Round 2
// 908.529 us; speedup vs baseline: 2.3115x; 2.3115x over previous
//
#include <hip/hip_runtime.h>
#include <hip/hip_bf16.h>

#define CDIM 256
#define MDIM 196
#define MATN (CDIM*CDIM)          // 65536
#define DTRI (CDIM*(CDIM+1)/2)    // 32896
#define PLANE 65536               // elements per bf16 plane
#define SLOT_STRIDE (2*PLANE)     // ushorts per batch per matrix slot (hi plane + lo plane)

typedef __attribute__((ext_vector_type(8))) short bf16x8;
typedef __attribute__((ext_vector_type(4))) float f32x4;

__device__ __forceinline__ unsigned short f2bf(float f) {
    unsigned int u = __builtin_bit_cast(unsigned int, f);
    u = u + 0x7fff + ((u >> 16) & 1);           // RNE
    return (unsigned short)(u >> 16);
}
__device__ __forceinline__ float bf2f(unsigned short h) {
    unsigned int u = ((unsigned int)h) << 16;
    return __builtin_bit_cast(float, u);
}

// ---------- per-row means over M ----------
__global__ void means_kernel(const float* __restrict__ x, float* __restrict__ means, int nrows) {
    int row  = blockIdx.x * 4 + (threadIdx.x >> 6);
    int lane = threadIdx.x & 63;
    if (row >= nrows) return;
    const float* xr = x + (size_t)row * MDIM;
    float s = 0.f;
    for (int m = lane; m < MDIM; m += 64) s += xr[m];
#pragma unroll
    for (int off = 32; off > 0; off >>= 1) s += __shfl_down(s, off);
    if (lane == 0) means[row] = s * (1.f / MDIM);
}

// ---------- covariance: A[b] = (1/M) x x^T - mu mu^T  -> hi/lo bf16 planes ----------
__global__ __launch_bounds__(256) void covpool_kernel(const float* __restrict__ x,
        const float* __restrict__ means, unsigned short* __restrict__ S0) {
    int b  = blockIdx.y;
    int r0 = (blockIdx.x >> 2) * 64;
    int c0 = (blockIdx.x & 3) * 64;
    const float* xb = x + (size_t)b * CDIM * MDIM;
    __shared__ float As[16][68];
    __shared__ float Bs[16][68];
    int tid = threadIdx.x;
    int ty = tid >> 4, tx = tid & 15;
    float acc[4][4] = {};
    int kl = tid & 15, m0 = tid >> 4;
    for (int k0 = 0; k0 < MDIM; k0 += 16) {
        int k = k0 + kl;
        bool kok = (k < MDIM);
#pragma unroll
        for (int i = 0; i < 4; i++) {
            int ml = m0 + 16 * i;
            As[kl][ml] = kok ? xb[(size_t)(r0 + ml) * MDIM + k] : 0.f;
            Bs[kl][ml] = kok ? xb[(size_t)(c0 + ml) * MDIM + k] : 0.f;
        }
        __syncthreads();
#pragma unroll
        for (int kk = 0; kk < 16; kk++) {
            float4 av = *(const float4*)&As[kk][ty * 4];
            float4 bv = *(const float4*)&Bs[kk][tx * 4];
            float aa[4] = {av.x, av.y, av.z, av.w};
            float bb[4] = {bv.x, bv.y, bv.z, bv.w};
#pragma unroll
            for (int i = 0; i < 4; i++)
#pragma unroll
                for (int j = 0; j < 4; j++)
                    acc[i][j] = fmaf(aa[i], bb[j], acc[i][j]);
        }
        __syncthreads();
    }
    const float* mub = means + (size_t)b * CDIM;
    float mi[4], mj[4];
#pragma unroll
    for (int i = 0; i < 4; i++) { mi[i] = mub[r0 + ty * 4 + i]; mj[i] = mub[c0 + tx * 4 + i]; }
    unsigned short* Ahi = S0 + (size_t)b * SLOT_STRIDE;
    unsigned short* Alo = Ahi + PLANE;
#pragma unroll
    for (int i = 0; i < 4; i++) {
        int r = r0 + ty * 4 + i;
        int c = c0 + tx * 4;
        unsigned short hs[4], ls[4];
#pragma unroll
        for (int j = 0; j < 4; j++) {
            float v = acc[i][j] * (1.f / MDIM) - mi[i] * mj[j];
            unsigned short h = f2bf(v);
            hs[j] = h;
            ls[j] = f2bf(v - bf2f(h));
        }
        *(uint2*)&Ahi[(size_t)r * CDIM + c] = *(uint2*)hs;
        *(uint2*)&Alo[(size_t)r * CDIM + c] = *(uint2*)ls;
    }
}

// ---------- trace per batch (from hi+lo planes) ----------
__global__ void trace_kernel(const unsigned short* __restrict__ S0, float* __restrict__ norm) {
    int b = blockIdx.x;
    int tid = threadIdx.x;
    const unsigned short* Ahi = S0 + (size_t)b * SLOT_STRIDE;
    const unsigned short* Alo = Ahi + PLANE;
    float v = bf2f(Ahi[(size_t)tid * 257]) + bf2f(Alo[(size_t)tid * 257]);
#pragma unroll
    for (int off = 32; off > 0; off >>= 1) v += __shfl_down(v, off);
    __shared__ float red[4];
    if ((tid & 63) == 0) red[tid >> 6] = v;
    __syncthreads();
    if (tid == 0) norm[b] = red[0] + red[1] + red[2] + red[3];
}

// ---------- Z0 = 1.5 I - 0.5 * (A / norm) ----------
__global__ void prep_kernel(const unsigned short* __restrict__ A, unsigned short* __restrict__ Z,
                            const float* __restrict__ norm, int bc) {
    int idx = blockIdx.x * 256 + threadIdx.x;   // one thread per 8 elements
    int total = bc * (MATN / 8);
    if (idx >= total) return;
    int b = idx >> 13;                          // MATN/8 = 8192
    int e0 = (idx & 8191) << 3;
    int r = e0 >> 8, c0 = e0 & 255;
    const unsigned short* Ahi = A + (size_t)b * SLOT_STRIDE;
    const unsigned short* Alo = Ahi + PLANE;
    unsigned short* Zhi = Z + (size_t)b * SLOT_STRIDE;
    unsigned short* Zlo = Zhi + PLANE;
    float inv = 1.f / norm[b];
    unsigned short h[8], l[8], zh[8], zl[8];
    *(uint4*)h = *(const uint4*)&Ahi[e0];
    *(uint4*)l = *(const uint4*)&Alo[e0];
#pragma unroll
    for (int k = 0; k < 8; k++) {
        float val = (bf2f(h[k]) + bf2f(l[k])) * inv;
        float z = ((r == c0 + k) ? 1.5f : 0.f) - 0.5f * val;
        unsigned short hh = f2bf(z);
        zh[k] = hh;
        zl[k] = f2bf(z - bf2f(hh));
    }
    *(uint4*)&Zhi[e0] = *(uint4*)zh;
    *(uint4*)&Zlo[e0] = *(uint4*)zl;
}

// ---------- batched MFMA GEMM on hi/lo bf16 planes ----------
// D[b] = s * (alpha * A[b]@B[b] + beta * C[b]);  s per mode {0:1, 1:1/norm, 2:sqrt(norm)}.
// B-operand read row-major relying on symmetry (all NS iterates are symmetric).
// If fcw != null: no D write; out[b0+b] += fc(triu(D)) via atomics.
__global__ __launch_bounds__(256) void bgemm_kernel(
        const unsigned short* __restrict__ Abase, const unsigned short* __restrict__ Bbase,
        const unsigned short* __restrict__ Cbase, unsigned short* __restrict__ Dbase,
        float alpha, float beta, int mode, const float* __restrict__ norm,
        const float* __restrict__ fcw, float* __restrict__ out, int b0, int bc) {
    __shared__ __align__(16) char lds[2][4][8192];   // [dbuf][Ah,Al,Bh,Bl][64 rows x 8 chunks x 16B]
    int tid = threadIdx.x;
    int lin = blockIdx.x;
    int b, tile;
    if ((bc & 7) == 0) {            // XCD-aware: keep each batch's 16 tiles on one XCD
        int xcd = lin & 7, i = lin >> 3, bpx = bc >> 3;
        b = xcd * bpx + (i >> 4);
        tile = i & 15;
    } else { b = lin >> 4; tile = lin & 15; }
    int r0 = (tile >> 2) * 64, c0 = (tile & 3) * 64;

    const unsigned short* Ab = Abase + (size_t)b * SLOT_STRIDE;
    const unsigned short* Bb = Bbase + (size_t)b * SLOT_STRIDE;
    const unsigned short* srcs[4] = { Ab + (size_t)r0 * CDIM, Ab + PLANE + (size_t)r0 * CDIM,
                                      Bb + (size_t)c0 * CDIM, Bb + PLANE + (size_t)c0 * CDIM };

    int w = tid >> 6, lane = tid & 63;
    int wr = w >> 1, wc = w & 1;
    int fr = lane & 15, kq = lane >> 4;

    f32x4 acc[2][2];
#pragma unroll
    for (int i = 0; i < 2; i++)
#pragma unroll
        for (int j = 0; j < 2; j++) acc[i][j] = (f32x4){0.f, 0.f, 0.f, 0.f};

    // LDS chunk (m, c) holds logical k-window (c ^ (m&7)); dest is wave-linear so
    // global_load_lds works; the swizzle lives in the per-lane GLOBAL address.
#define STAGE(buf, k0) do {                                                              \
    _Pragma("unroll")                                                                    \
    for (int p = 0; p < 4; p++) {                                                        \
        _Pragma("unroll")                                                                \
        for (int s = 0; s < 2; s++) {                                                    \
            int cid = s * 256 + tid;                                                     \
            int m = cid >> 3;                                                            \
            int kg = (cid & 7) ^ (m & 7);                                                \
            const unsigned short* g = srcs[p] + (size_t)m * CDIM + (k0) + kg * 8;        \
            void* lp = (void*)&lds[buf][p][(s * 256 + (tid & ~63)) * 16];                \
            __builtin_amdgcn_global_load_lds(                                            \
                (const __attribute__((address_space(1))) void*)g,                        \
                (__attribute__((address_space(3))) void*)(unsigned int)(unsigned long long)lp, \
                16, 0, 0);                                                               \
        }                                                                                \
    } } while (0)

    STAGE(0, 0);
    __syncthreads();

    int cur = 0;
    for (int k0 = 0; k0 < CDIM; k0 += 64) {
        if (k0 + 64 < CDIM) STAGE(cur ^ 1, k0 + 64);
#pragma unroll
        for (int h = 0; h < 2; h++) {
            bf16x8 fAh[2], fAl[2], fBh[2], fBl[2];
#pragma unroll
            for (int i = 0; i < 2; i++) {
                int mL = wr * 32 + i * 16 + fr;
                int ca = ((h * 4 + kq) ^ (mL & 7));
                fAh[i] = *(const bf16x8*)&lds[cur][0][(mL * 8 + ca) * 16];
                fAl[i] = *(const bf16x8*)&lds[cur][1][(mL * 8 + ca) * 16];
                int nL = wc * 32 + i * 16 + fr;
                int cb = ((h * 4 + kq) ^ (nL & 7));
                fBh[i] = *(const bf16x8*)&lds[cur][2][(nL * 8 + cb) * 16];
                fBl[i] = *(const bf16x8*)&lds[cur][3][(nL * 8 + cb) * 16];
            }
#pragma unroll
            for (int i = 0; i < 2; i++)
#pragma unroll
                for (int j = 0; j < 2; j++) {
                    acc[i][j] = __builtin_amdgcn_mfma_f32_16x16x32_bf16(fAh[i], fBh[j], acc[i][j], 0, 0, 0);
                    acc[i][j] = __builtin_amdgcn_mfma_f32_16x16x32_bf16(fAh[i], fBl[j], acc[i][j], 0, 0, 0);
                    acc[i][j] = __builtin_amdgcn_mfma_f32_16x16x32_bf16(fAl[i], fBh[j], acc[i][j], 0, 0, 0);
                }
        }
        __syncthreads();
        cur ^= 1;
    }

    float s = 1.f;
    if (mode == 1) s = 1.f / norm[b];
    else if (mode == 2) s = sqrtf(norm[b]);

    const unsigned short* Chi = Cbase ? Cbase + (size_t)b * SLOT_STRIDE : nullptr;
    const unsigned short* Clo = Chi ? Chi + PLANE : nullptr;

    if (fcw == nullptr) {
        unsigned short* Dhi = Dbase + (size_t)b * SLOT_STRIDE;
        unsigned short* Dlo = Dhi + PLANE;
#pragma unroll
        for (int i = 0; i < 2; i++)
#pragma unroll
            for (int j = 0; j < 2; j++)
#pragma unroll
                for (int rr = 0; rr < 4; rr++) {
                    int row = r0 + wr * 32 + i * 16 + kq * 4 + rr;
                    int col = c0 + wc * 32 + j * 16 + fr;
                    float v = alpha * acc[i][j][rr];
                    if (Chi) v += beta * (bf2f(Chi[(size_t)row * CDIM + col]) + bf2f(Clo[(size_t)row * CDIM + col]));
                    v *= s;
                    unsigned short hh = f2bf(v);
                    Dhi[(size_t)row * CDIM + col] = hh;
                    Dlo[(size_t)row * CDIM + col] = f2bf(v - bf2f(hh));
                }
    } else {
        float s0 = 0.f, s1 = 0.f;
#pragma unroll
        for (int i = 0; i < 2; i++)
#pragma unroll
            for (int j = 0; j < 2; j++)
#pragma unroll
                for (int rr = 0; rr < 4; rr++) {
                    int row = r0 + wr * 32 + i * 16 + kq * 4 + rr;
                    int col = c0 + wc * 32 + j * 16 + fr;
                    float v = alpha * acc[i][j][rr];
                    if (Chi) v += beta * (bf2f(Chi[(size_t)row * CDIM + col]) + bf2f(Clo[(size_t)row * CDIM + col]));
                    v *= s;
                    if (col >= row) {
                        int t = row * CDIM - (row * (row - 1)) / 2 + (col - row);
                        s0 = fmaf(v, fcw[t], s0);
                        s1 = fmaf(v, fcw[DTRI + t], s1);
                    }
                }
#pragma unroll
        for (int off = 32; off > 0; off >>= 1) { s0 += __shfl_down(s0, off); s1 += __shfl_down(s1, off); }
        __syncthreads();
        float* red = (float*)&lds[0][0][0];
        if (lane == 0) { red[w * 2] = s0; red[w * 2 + 1] = s1; }
        __syncthreads();
        if (tid == 0) {
            atomicAdd(&out[(size_t)(b0 + b) * 2 + 0], red[0] + red[2] + red[4] + red[6]);
            atomicAdd(&out[(size_t)(b0 + b) * 2 + 1], red[1] + red[3] + red[5] + red[7]);
        }
    }
#undef STAGE
}

// ---------- out init with bias ----------
__global__ void init_out(float* __restrict__ out, const float* __restrict__ bias, int n) {
    int i = blockIdx.x * 256 + threadIdx.x;
    if (i < n) out[i] = bias[i & 1];
}

extern "C" void kernel_launch(void* const* d_in, const int* in_sizes, int n_in,
                              void* d_out, int out_size, void* d_ws, size_t ws_size,
                              hipStream_t stream) {
    const float* x    = (const float*)d_in[0];
    const float* fc_w = (const float*)d_in[1];
    const float* fc_b = (const float*)d_in[2];
    float* out = (float*)d_out;
    int B = in_sizes[0] / (CDIM * MDIM);

    size_t per_b = (size_t)4 * SLOT_STRIDE * sizeof(unsigned short)
                 + (size_t)CDIM * sizeof(float) + sizeof(float);
    int Bc = B;
    while (Bc > 1 && (size_t)Bc * per_b > ws_size) Bc >>= 1;

    char* p = (char*)d_ws;
    unsigned short* slot[4];
    for (int i = 0; i < 4; i++) { slot[i] = (unsigned short*)p; p += (size_t)Bc * SLOT_STRIDE * sizeof(unsigned short); }
    float* means = (float*)p; p += (size_t)Bc * CDIM * sizeof(float);
    float* norm  = (float*)p;

    init_out<<<(out_size + 255) / 256, 256, 0, stream>>>(out, fc_b, out_size);

    for (int b0 = 0; b0 < B; b0 += Bc) {
        int bc = (Bc < B - b0) ? Bc : (B - b0);
        const float* xb = x + (size_t)b0 * CDIM * MDIM;
        int nrows = bc * CDIM;

        means_kernel<<<(nrows + 3) / 4, 256, 0, stream>>>(xb, means, nrows);
        covpool_kernel<<<dim3(16, bc), 256, 0, stream>>>(xb, means, slot[0]);
        trace_kernel<<<bc, 256, 0, stream>>>(slot[0], norm);
        prep_kernel<<<bc * 32, 256, 0, stream>>>(slot[0], slot[1], norm, bc);

        unsigned short* A  = slot[0];
        unsigned short* z  = slot[1];
        unsigned short* t1 = slot[2];
        unsigned short* t2 = slot[3];
        int g = 16 * bc;
        for (int it = 0; it < 3; it++) {
            bgemm_kernel<<<g, 256, 0, stream>>>(A,  z,  nullptr, t1, 1.f,  0.f, 1, norm, nullptr, nullptr, b0, bc);
            bgemm_kernel<<<g, 256, 0, stream>>>(z,  t1, nullptr, t2, 1.f,  0.f, 0, norm, nullptr, nullptr, b0, bc);
            bgemm_kernel<<<g, 256, 0, stream>>>(t2, z,  z,       t1, -0.5f, 1.5f, 0, norm, nullptr, nullptr, b0, bc);
            unsigned short* tmp = z; z = t1; t1 = tmp;
        }
        bgemm_kernel<<<g, 256, 0, stream>>>(A, z,  nullptr, t1, 1.f,  0.f, 1, norm, nullptr, nullptr, b0, bc);
        bgemm_kernel<<<g, 256, 0, stream>>>(z, t1, nullptr, t2, 1.f,  0.f, 0, norm, nullptr, nullptr, b0, bc);
        bgemm_kernel<<<g, 256, 0, stream>>>(t1, t2, t1, nullptr, -0.5f, 1.5f, 2, norm, fc_w, out, b0, bc);
    }
}